// Round 1
// baseline (730.957 us; speedup 1.0000x reference)
//
#include <hip/hip_runtime.h>
#include <math.h>

#define NRAYS  524288
#define HIDDEN 128

// One thread per ray. Weights staged in LDS (broadcast reads).
// Softplus: max(z,0) + log1p(exp(-|z|)) via hw exp2/log2 — matches
// jax.nn.softplus (= logaddexp(x,0)) stable form.
__global__ __launch_bounds__(256) void raymarch_kernel(
    const float* __restrict__ r,
    const float* __restrict__ pivot,
    const float* __restrict__ W1,
    const float* __restrict__ b1,
    const float* __restrict__ W2,
    const float* __restrict__ b2,
    const int*   __restrict__ n_iter,
    float* __restrict__ out)
{
    __shared__ float4 sw[HIDDEN];   // {W1[0][j], W1[1][j], W1[2][j], b1[j]}
    __shared__ float  sv[HIDDEN];   // W2[j]

    const int tid = threadIdx.x;
    for (int j = tid; j < HIDDEN; j += blockDim.x) {
        sw[j] = make_float4(W1[0 * HIDDEN + j],
                            W1[1 * HIDDEN + j],
                            W1[2 * HIDDEN + j],
                            b1[j]);
        sv[j] = W2[j];
    }
    __syncthreads();

    const int i = blockIdx.x * blockDim.x + tid;
    if (i >= NRAYS) return;

    const float4 rv = ((const float4*)r)[i];
    const float nrm = sqrtf(rv.x * rv.x + rv.y * rv.y + rv.z * rv.z + rv.w * rv.w);
    const float inv = 1.0f / nrm;
    const float rn0 = rv.x * inv;
    const float rn1 = rv.y * inv;
    const float rn2 = rv.z * inv;
    const float rn3 = rv.w * inv;

    const float p0 = pivot[0], p1 = pivot[1], p2 = pivot[2];
    const float bb2 = b2[0];
    const int   T = n_iter[0];

    float alpha = 0.0f;
    for (int t = 0; t < T; ++t) {
        const float x0 = alpha * rn0;                 // pivot_ext[0] == 0
        const float x1 = fmaf(alpha, rn1, p0);
        const float x2 = fmaf(alpha, rn2, p1);
        const float x3 = fmaf(alpha, rn3, p2);
        float acc = bb2;
        #pragma unroll 16
        for (int j = 0; j < HIDDEN; ++j) {
            const float4 w = sw[j];
            const float z = fmaf(x1, w.x, fmaf(x2, w.y, fmaf(x3, w.z, w.w)));
            // stable softplus: max(z,0) + log(1 + exp(-|z|))
            const float e = __expf(-fabsf(z));        // v_mul(abs,neg mods) + v_exp
            const float h = fmaxf(z, 0.0f) + __logf(1.0f + e);
            acc = fmaf(h, sv[j], acc);
        }
        const float s = acc;
        const float a = fabsf(s);
        const float ext = fmaxf(fmaxf(s, x0 - a), -a - x0);
        alpha -= ext;
    }

    out[3 * i + 0] = fmaf(alpha, rn1, p0);
    out[3 * i + 1] = fmaf(alpha, rn2, p1);
    out[3 * i + 2] = fmaf(alpha, rn3, p2);
}

extern "C" void kernel_launch(void* const* d_in, const int* in_sizes, int n_in,
                              void* d_out, int out_size, void* d_ws, size_t ws_size,
                              hipStream_t stream) {
    const float* r     = (const float*)d_in[0];
    const float* pivot = (const float*)d_in[1];
    const float* W1    = (const float*)d_in[2];
    const float* b1    = (const float*)d_in[3];
    const float* W2    = (const float*)d_in[4];
    const float* b2    = (const float*)d_in[5];
    const int*   nit   = (const int*)d_in[6];
    float* out = (float*)d_out;

    const int block = 256;
    const int grid  = (NRAYS + block - 1) / block;
    raymarch_kernel<<<grid, block, 0, stream>>>(r, pivot, W1, b1, W2, b2, nit, out);
}

// Round 2
// 712.373 us; speedup vs baseline: 1.0261x; 1.0261x over previous
//
#include <hip/hip_runtime.h>
#include <math.h>

#define NRAYS  524288
#define HIDDEN 128

extern "C" __device__ float __ocml_native_exp2_f32(float);
extern "C" __device__ float __ocml_native_log2_f32(float);

// Prescale into ws: ws[0:128) = b1*log2e, ws[128:256) = W2*ln2.
// (log2-domain softplus: softplus(z) = ln2*(max(z',0)+log2(1+2^-|z'|)),
//  z' = z*log2e; the ln2 is folded into W2.)
__global__ void prep_kernel(const float* __restrict__ b1,
                            const float* __restrict__ W2,
                            float* __restrict__ ws) {
    int j = threadIdx.x;
    ws[j]       = b1[j] * 1.44269504088896340736f;  // log2(e)
    ws[128 + j] = W2[j] * 0.69314718055994530942f;  // ln(2)
}

__global__ __launch_bounds__(256) void raymarch_kernel(
    const float* __restrict__ r,
    const float* __restrict__ pivot,
    const float* __restrict__ W1,     // [3][128] row-major, original scale
    const float* __restrict__ b2,
    const int*   __restrict__ n_iter,
    const float* __restrict__ ws,     // b1', v'
    float* __restrict__ out)
{
    const float LOG2E = 1.44269504088896340736f;
    const float* __restrict__ b1s = ws;        // b1 * log2e
    const float* __restrict__ vw  = ws + 128;  // W2 * ln2

    const int i = blockIdx.x * 256 + threadIdx.x;

    const float4 rv = ((const float4*)r)[i];
    const float inv = 1.0f / sqrtf(rv.x*rv.x + rv.y*rv.y + rv.z*rv.z + rv.w*rv.w);
    const float rn0 = rv.x*inv, rn1 = rv.y*inv, rn2 = rv.z*inv, rn3 = rv.w*inv;
    const float p0 = pivot[0], p1 = pivot[1], p2 = pivot[2];
    // scaled (log2-domain) ray/pivot for z' = x'.w + b1'
    const float rs1 = rn1*LOG2E, rs2 = rn2*LOG2E, rs3 = rn3*LOG2E;
    const float ps0 = p0*LOG2E,  ps1 = p1*LOG2E,  ps2 = p2*LOG2E;
    const float bb2 = b2[0];
    const int   T   = n_iter[0];

    // Per-ray collapse precompute: z'_j = alpha*d_j + c_j (log2 units).
    // Once |alpha|*|d_j| > 40+|c_j| for all j: softplus==relu to 2^-40 and
    // the active set is sign(alpha*d_j) -> s = alpha*P(+-) + Q(+-) + b2.
    float Pp = 0.f, Qp = 0.f, Pa = 0.f, Qa = 0.f, A = 0.f;
    #pragma unroll 8
    for (int j = 0; j < HIDDEN; ++j) {
        const float w0 = W1[j], w1 = W1[HIDDEN + j], w2 = W1[2*HIDDEN + j];
        const float d = fmaf(rs1, w0, fmaf(rs2, w1, rs3 * w2));
        const float c = fmaf(ps0, w0, fmaf(ps1, w1, fmaf(ps2, w2, b1s[j])));
        const float v = vw[j];
        const float vd = v * d, vc = v * c;
        const bool pos = d > 0.0f;
        Pp += pos ? vd : 0.0f;
        Qp += pos ? vc : 0.0f;
        Pa += vd;
        Qa += vc;
        A = fmaxf(A, __fdividef(40.0f + fabsf(c), fabsf(d)));
    }
    const float Pm = Pa - Pp, Qm = Qa - Qp;

    float alpha = 0.0f;
    for (int t = 0; t < T; ++t) {
        float s;
        const int fast = __builtin_amdgcn_readfirstlane((int)__all(fabsf(alpha) > A));
        if (fast) {
            const float P = (alpha > 0.0f) ? Pp : Pm;
            const float Q = (alpha > 0.0f) ? Qp : Qm;
            s = fmaf(alpha, P, Q) + bb2;
        } else {
            const float x1 = fmaf(alpha, rs1, ps0);
            const float x2 = fmaf(alpha, rs2, ps1);
            const float x3 = fmaf(alpha, rs3, ps2);
            float acc = bb2;
            #pragma unroll 8
            for (int j = 0; j < HIDDEN; ++j) {
                const float z = fmaf(x1, W1[j],
                                fmaf(x2, W1[HIDDEN + j],
                                fmaf(x3, W1[2*HIDDEN + j], b1s[j])));
                const float e = __ocml_native_exp2_f32(-fabsf(z));
                const float l = __ocml_native_log2_f32(1.0f + e);
                acc = fmaf(fmaxf(z, 0.0f) + l, vw[j], acc);
            }
            s = acc;
        }
        const float a  = fabsf(s);
        const float x0 = alpha * rn0;
        const float ext = fmaxf(fmaxf(s, x0 - a), -a - x0);
        alpha -= ext;
    }

    out[3*i + 0] = fmaf(alpha, rn1, p0);
    out[3*i + 1] = fmaf(alpha, rn2, p1);
    out[3*i + 2] = fmaf(alpha, rn3, p2);
}

extern "C" void kernel_launch(void* const* d_in, const int* in_sizes, int n_in,
                              void* d_out, int out_size, void* d_ws, size_t ws_size,
                              hipStream_t stream) {
    const float* r     = (const float*)d_in[0];
    const float* pivot = (const float*)d_in[1];
    const float* W1    = (const float*)d_in[2];
    const float* b1    = (const float*)d_in[3];
    const float* W2    = (const float*)d_in[4];
    const float* b2    = (const float*)d_in[5];
    const int*   nit   = (const int*)d_in[6];
    float* out = (float*)d_out;
    float* ws  = (float*)d_ws;

    prep_kernel<<<1, 128, 0, stream>>>(b1, W2, ws);
    raymarch_kernel<<<NRAYS / 256, 256, 0, stream>>>(r, pivot, W1, b2, nit, ws, out);
}

// Round 3
// 351.105 us; speedup vs baseline: 2.0819x; 2.0289x over previous
//
#include <hip/hip_runtime.h>
#include <math.h>

#define NRAYS   524288
#define HIDDEN  128
#define LOG2E_F 1.44269504088896340736f
#define LN2_F   0.69314718055994530942f
#define THRESH  40   // compacted path when n_slow <= THRESH

extern "C" __device__ float __ocml_native_exp2_f32(float);
extern "C" __device__ float __ocml_native_log2_f32(float);

// log2-domain softplus: natural softplus(z) = ln2*(max(z',0)+log2(1+2^-|z'|)),
// z' = z*log2e. The ln2 is folded into W2 (vw). Input here is z'.
__device__ __forceinline__ float softplus2(float z) {
    const float e = __ocml_native_exp2_f32(-fabsf(z));
    return fmaxf(z, 0.0f) + __ocml_native_log2_f32(1.0f + e);
}

// ws layout: [0:128) b1*log2e | [128:256) W2*ln2 | [256] s0 = s(alpha=0)
__global__ void prep_kernel(const float* __restrict__ pivot,
                            const float* __restrict__ W1,
                            const float* __restrict__ b1,
                            const float* __restrict__ W2,
                            const float* __restrict__ b2,
                            float* __restrict__ ws) {
    __shared__ float red[HIDDEN];
    const int j = threadIdx.x;
    const float b1s = b1[j] * LOG2E_F;
    const float vw  = W2[j] * LN2_F;
    ws[j]          = b1s;
    ws[HIDDEN + j] = vw;
    const float ps0 = pivot[0] * LOG2E_F;
    const float ps1 = pivot[1] * LOG2E_F;
    const float ps2 = pivot[2] * LOG2E_F;
    const float c = fmaf(ps0, W1[j],
                    fmaf(ps1, W1[HIDDEN + j],
                    fmaf(ps2, W1[2*HIDDEN + j], b1s)));
    red[j] = softplus2(c) * vw;
    __syncthreads();
    if (j == 0) {
        float s = b2[0];
        for (int k = 0; k < HIDDEN; ++k) s += red[k];
        ws[2 * HIDDEN] = s;   // at alpha=0: ext = s0, so alpha_1 = -s0
    }
}

__global__ __launch_bounds__(256) void raymarch_kernel(
    const float* __restrict__ r,
    const float* __restrict__ pivot,
    const float* __restrict__ W1,     // [3][128] row-major
    const float* __restrict__ b2,
    const int*   __restrict__ n_iter,
    const float* __restrict__ ws,
    float* __restrict__ out)
{
    const float* __restrict__ b1s = ws;
    const float* __restrict__ vw  = ws + HIDDEN;

    const int i    = blockIdx.x * 256 + threadIdx.x;
    const int lane = threadIdx.x & 63;

    const float4 rv = ((const float4*)r)[i];
    const float inv = 1.0f / sqrtf(rv.x*rv.x + rv.y*rv.y + rv.z*rv.z + rv.w*rv.w);
    const float rn0 = rv.x*inv, rn1 = rv.y*inv, rn2 = rv.z*inv, rn3 = rv.w*inv;
    const float p0 = pivot[0], p1 = pivot[1], p2 = pivot[2];
    const float rs1 = rn1*LOG2E_F, rs2 = rn2*LOG2E_F, rs3 = rn3*LOG2E_F;
    const float ps0 = p0*LOG2E_F,  ps1 = p1*LOG2E_F,  ps2 = p2*LOG2E_F;
    const float bb2 = b2[0];
    const int   T   = n_iter[0];

    // Per-lane register-cached weights for the compacted path:
    // lane handles hidden units (lane) and (lane+64). Coalesced, one-time.
    const float wa0 = W1[lane],       wa1 = W1[HIDDEN+lane],    wa2 = W1[2*HIDDEN+lane];
    const float wa3 = b1s[lane],      wa4 = vw[lane];
    const float wb0 = W1[64+lane],    wb1 = W1[HIDDEN+64+lane], wb2 = W1[2*HIDDEN+64+lane];
    const float wb3 = b1s[64+lane],   wb4 = vw[64+lane];

    // Linear-regime collapse: z'_j = alpha*d_j + c_j. Once |alpha| > A
    // (all units hard): s = alpha*P(sign) + Q(sign) + b2.
    float Pp = 0.f, Qp = 0.f, Pa = 0.f, Qa = 0.f, A = 0.f;
    #pragma unroll 8
    for (int j = 0; j < HIDDEN; ++j) {
        const float w0 = W1[j], w1 = W1[HIDDEN + j], w2 = W1[2*HIDDEN + j];
        const float d = fmaf(rs1, w0, fmaf(rs2, w1, rs3 * w2));
        const float c = fmaf(ps0, w0, fmaf(ps1, w1, fmaf(ps2, w2, b1s[j])));
        const float v = vw[j];
        const float vd = v * d, vc = v * c;
        const bool pos = d > 0.0f;
        Pp += pos ? vd : 0.0f;
        Qp += pos ? vc : 0.0f;
        Pa += vd;
        Qa += vc;
        A = fmaxf(A, __fdividef(30.0f + fabsf(c), fabsf(d)));  // 2^-30 softplus tail
    }
    const float Pm = Pa - Pp, Qm = Qa - Qp;

    float alpha = 0.0f;
    if (T > 0) {
        alpha = -ws[2 * HIDDEN];   // iteration t=0 is ray-independent
        for (int t = 1; t < T; ++t) {
            const bool pos = alpha > 0.0f;
            float s = fmaf(alpha, pos ? Pp : Pm, pos ? Qp : Qm) + bb2;
            const bool slow = fabsf(alpha) <= A;
            unsigned long long m = __ballot(slow);
            if (m) {
                const float x1 = fmaf(alpha, rs1, ps0);
                const float x2 = fmaf(alpha, rs2, ps1);
                const float x3 = fmaf(alpha, rs3, ps2);
                if (__popcll(m) > THRESH) {
                    // nearly everyone soft: classic full loop (uniform j -> s_loads)
                    float acc = bb2;
                    #pragma unroll 8
                    for (int j = 0; j < HIDDEN; ++j) {
                        const float z = fmaf(x1, W1[j],
                                        fmaf(x2, W1[HIDDEN + j],
                                        fmaf(x3, W1[2*HIDDEN + j], b1s[j])));
                        acc = fmaf(softplus2(z), vw[j], acc);
                    }
                    if (slow) s = acc;
                } else {
                    // wave-local compaction: whole wave evaluates one slow ray
                    // at a time, 2 units/lane from registers, butterfly reduce.
                    while (m) {
                        const int l = __ffsll((long long)m) - 1;
                        m &= m - 1;
                        const float bx1 = __shfl(x1, l);
                        const float bx2 = __shfl(x2, l);
                        const float bx3 = __shfl(x3, l);
                        const float z1 = fmaf(bx1, wa0, fmaf(bx2, wa1, fmaf(bx3, wa2, wa3)));
                        const float z2 = fmaf(bx1, wb0, fmaf(bx2, wb1, fmaf(bx3, wb2, wb3)));
                        float part = fmaf(softplus2(z1), wa4, softplus2(z2) * wb4);
                        #pragma unroll
                        for (int off = 32; off; off >>= 1)
                            part += __shfl_xor(part, off);
                        if (lane == l) s = part + bb2;
                    }
                }
            }
            const float a  = fabsf(s);
            const float x0 = alpha * rn0;
            alpha -= fmaxf(fmaxf(s, x0 - a), -a - x0);
        }
    }

    out[3*i + 0] = fmaf(alpha, rn1, p0);
    out[3*i + 1] = fmaf(alpha, rn2, p1);
    out[3*i + 2] = fmaf(alpha, rn3, p2);
}

extern "C" void kernel_launch(void* const* d_in, const int* in_sizes, int n_in,
                              void* d_out, int out_size, void* d_ws, size_t ws_size,
                              hipStream_t stream) {
    const float* r     = (const float*)d_in[0];
    const float* pivot = (const float*)d_in[1];
    const float* W1    = (const float*)d_in[2];
    const float* b1    = (const float*)d_in[3];
    const float* W2    = (const float*)d_in[4];
    const float* b2    = (const float*)d_in[5];
    const int*   nit   = (const int*)d_in[6];
    float* out = (float*)d_out;
    float* ws  = (float*)d_ws;

    prep_kernel<<<1, HIDDEN, 0, stream>>>(pivot, W1, b1, W2, b2, ws);
    raymarch_kernel<<<NRAYS / 256, 256, 0, stream>>>(r, pivot, W1, b2, nit, ws, out);
}